// Round 2
// baseline (640.060 us; speedup 1.0000x reference)
//
#include <hip/hip_runtime.h>

typedef int v4i __attribute__((ext_vector_type(4)));

static constexpr int K_DIM = 4096;
static constexpr int BM = 256, BN = 256, BK = 128;   // i8: 128 B per K-slab row
static constexpr int NT = K_DIM / BK;                 // 32 K-tiles

// ---------------- per-token dynamic quantization ----------------
__global__ __launch_bounds__(256) void quant_kernel(const float* __restrict__ x,
                                                    signed char* __restrict__ xq,
                                                    float* __restrict__ xs) {
    const int token = blockIdx.x;
    const float4* row = (const float4*)(x + (size_t)token * K_DIM);
    const int t = threadIdx.x;
    float4 v[4];
    float m = 0.f;
#pragma unroll
    for (int i = 0; i < 4; ++i) {
        v[i] = row[t * 4 + i];
        m = fmaxf(m, fabsf(v[i].x));
        m = fmaxf(m, fabsf(v[i].y));
        m = fmaxf(m, fabsf(v[i].z));
        m = fmaxf(m, fabsf(v[i].w));
    }
#pragma unroll
    for (int d = 32; d > 0; d >>= 1) m = fmaxf(m, __shfl_xor(m, d));
    __shared__ float red[4];
    if ((t & 63) == 0) red[t >> 6] = m;
    __syncthreads();
    const float am = fmaxf(fmaxf(red[0], red[1]), fmaxf(red[2], red[3]));
    const float s = fmaxf(am, 1e-8f) * (1.0f / 127.0f);
    const float inv = 127.0f / fmaxf(am, 1e-8f);

    int pk[4];
#pragma unroll
    for (int i = 0; i < 4; ++i) {
        int q0 = (int)fminf(127.f, fmaxf(-127.f, rintf(v[i].x * inv)));
        int q1 = (int)fminf(127.f, fmaxf(-127.f, rintf(v[i].y * inv)));
        int q2 = (int)fminf(127.f, fmaxf(-127.f, rintf(v[i].z * inv)));
        int q3 = (int)fminf(127.f, fmaxf(-127.f, rintf(v[i].w * inv)));
        pk[i] = (q0 & 255) | ((q1 & 255) << 8) | ((q2 & 255) << 16) | (q3 << 24);
    }
    ((int4*)(xq + (size_t)token * K_DIM))[t] = make_int4(pk[0], pk[1], pk[2], pk[3]);
    if (t == 0) xs[token] = s;
}

// ---------------- weight repack: int32 -> packed int8 ----------------
__global__ __launch_bounds__(256) void repack_kernel(const int* __restrict__ w32,
                                                     int4* __restrict__ w8,
                                                     int n16) {
    const int idx = blockIdx.x * 256 + threadIdx.x;
    if (idx >= n16) return;
    const int4* src = (const int4*)w32 + (size_t)idx * 4;
    int4 a = src[0], b = src[1], c = src[2], d = src[3];
    int p0 = (a.x & 255) | ((a.y & 255) << 8) | ((a.z & 255) << 16) | (a.w << 24);
    int p1 = (b.x & 255) | ((b.y & 255) << 8) | ((b.z & 255) << 16) | (b.w << 24);
    int p2 = (c.x & 255) | ((c.y & 255) << 8) | ((c.z & 255) << 16) | (c.w << 24);
    int p3 = (d.x & 255) | ((d.y & 255) << 8) | ((d.z & 255) << 16) | (d.w << 24);
    w8[idx] = make_int4(p0, p1, p2, p3);
}

// -------- frag-load / MFMA macros (all indices compile-time after unroll) ----
#define LOADA(SRC, MH, DST)                                                          \
    _Pragma("unroll") for (int mi = 0; mi < 4; ++mi) {                               \
        DST[mi][0] = *(const v4i*)&SRC[arowb + ((MH)*64 + mi*16)*BK + (kq ^ sw)];    \
        DST[mi][1] = *(const v4i*)&SRC[arowb + ((MH)*64 + mi*16)*BK + ((64+kq) ^ sw)]; \
    }
#define LOADB(SRC, NH, DST)                                                          \
    _Pragma("unroll") for (int ni = 0; ni < 2; ++ni) {                               \
        DST[ni][0] = *(const v4i*)&SRC[browb + ((NH)*32 + ni*16)*BK + (kq ^ sw)];    \
        DST[ni][1] = *(const v4i*)&SRC[browb + ((NH)*32 + ni*16)*BK + ((64+kq) ^ sw)]; \
    }
#define MMQ(MH, NH, AF, BF)                                                          \
    _Pragma("unroll") for (int mi = 0; mi < 4; ++mi)                                 \
    _Pragma("unroll") for (int ni = 0; ni < 2; ++ni) {                               \
        acc[(MH)*4+mi][(NH)*2+ni] = __builtin_amdgcn_mfma_i32_16x16x64_i8(           \
            AF[mi][0], BF[ni][0], acc[(MH)*4+mi][(NH)*2+ni], 0, 0, 0);               \
        acc[(MH)*4+mi][(NH)*2+ni] = __builtin_amdgcn_mfma_i32_16x16x64_i8(           \
            AF[mi][1], BF[ni][1], acc[(MH)*4+mi][(NH)*2+ni], 0, 0, 0);               \
    }

// ---------------- int8 MFMA GEMM, 256x256 tile, 8-phase schedule ----------------
__global__ __launch_bounds__(512, 2) void gemm_kernel(const signed char* __restrict__ xq,
                                                      const signed char* __restrict__ w8,
                                                      const float* __restrict__ xs,
                                                      const float* __restrict__ scale,
                                                      const float* __restrict__ bias,
                                                      float* __restrict__ out,
                                                      int N) {
    __shared__ __align__(16) signed char sA[2][BM * BK];   // 2 x 32 KB
    __shared__ __align__(16) signed char sB[2][BN * BK];   // 2 x 32 KB  (128 KiB total)

    const int tid = threadIdx.x;
    const int lane = tid & 63;
    const int wid = tid >> 6;          // 8 waves: 2(M) x 4(N)
    const int wm = wid >> 2;
    const int wn = wid & 3;

    // T1: XCD-aware bijective swizzle (grid = 43 x 32 = 1376, 1376 % 8 == 0)
    const int nwg = gridDim.x * gridDim.y;
    int flat = blockIdx.y * gridDim.x + blockIdx.x;
    if ((nwg & 7) == 0) flat = (flat & 7) * (nwg >> 3) + (flat >> 3);
    const int by = flat % gridDim.y;          // M-block (fastest within chunk -> B-panel reuse)
    const int bx = flat / gridDim.y;          // N-block
    const int m0 = by * BM;
    const int n0 = bx * BN;

    v4i acc[8][4];
    const v4i vzero = {0, 0, 0, 0};
#pragma unroll
    for (int i = 0; i < 8; ++i)
#pragma unroll
        for (int j = 0; j < 4; ++j) acc[i][j] = vzero;

    // staging geometry: one issue = 512 thr x 16 B = 64 rows; inverse-swizzled source col
    const int srow8 = tid >> 3;                               // 0..63 within issue
    const int scol = (((tid & 7) ^ (srow8 & 7)) << 4);
    const signed char* gA = xq + (size_t)m0 * K_DIM;
    const signed char* gB = w8 + (size_t)n0 * K_DIM;

    auto stageA = [&](int buf, int half, int k0) {
#pragma unroll
        for (int i = 0; i < 2; ++i) {
            const int row = half * 128 + i * 64 + srow8;
            const signed char* src = gA + (size_t)row * K_DIM + k0 + scol;
            __builtin_amdgcn_global_load_lds(
                (const __attribute__((address_space(1))) void*)src,
                (__attribute__((address_space(3))) void*)&sA[buf][half * 16384 + i * 8192 + wid * 1024],
                16, 0, 0);
        }
    };
    auto stageB = [&](int buf, int half, int k0) {
#pragma unroll
        for (int i = 0; i < 2; ++i) {
            const int row = half * 128 + i * 64 + srow8;
            const signed char* src = gB + (size_t)row * K_DIM + k0 + scol;
            __builtin_amdgcn_global_load_lds(
                (const __attribute__((address_space(1))) void*)src,
                (__attribute__((address_space(3))) void*)&sB[buf][half * 16384 + i * 8192 + wid * 1024],
                16, 0, 0);
        }
    };

    // read-side swizzle constants
    const int sw = (lane & 7) << 4;                 // row&7 of frag rows == lane&7
    const int kq = (lane >> 4) << 4;                // k quarter: 0,16,32,48
    const int arowb = (wm * 128 + (lane & 15)) * BK;
    const int browb = (wn * 64 + (lane & 15)) * BK;

    v4i a[4][2], b0f[2][2], b1f[2][2];

    // prologue: stage K-tile 0 fully into buf 0, drain, publish
    stageA(0, 0, 0); stageA(0, 1, 0); stageB(0, 0, 0); stageB(0, 1, 0);
    asm volatile("s_waitcnt vmcnt(0)" ::: "memory");
    __builtin_amdgcn_s_barrier();

    for (int kt = 0; kt < NT - 1; ++kt) {
        const int db = kt & 1;
        const int k1 = (kt + 1) * BK;
        const signed char* A = sA[db];
        const signed char* B = sB[db];

        // ---- phase 0: reads {A-half0, B-half0}; stages A-half0(kt+1); vmcnt(4)
        LOADA(A, 0, a);
        LOADB(B, 0, b0f);
        stageA(db ^ 1, 0, k1);
        asm volatile("s_waitcnt vmcnt(4)" ::: "memory");
        __builtin_amdgcn_s_barrier();
        __builtin_amdgcn_s_setprio(1);
        MMQ(0, 0, a, b0f);
        __builtin_amdgcn_s_setprio(0);
        __builtin_amdgcn_s_barrier();

        // ---- phase 1: reads {B-half1}; stages B-half0(kt+1); vmcnt(4)
        LOADB(B, 1, b1f);
        stageB(db ^ 1, 0, k1);
        asm volatile("s_waitcnt vmcnt(4)" ::: "memory");
        __builtin_amdgcn_s_barrier();
        __builtin_amdgcn_s_setprio(1);
        MMQ(0, 1, a, b1f);
        __builtin_amdgcn_s_setprio(0);
        __builtin_amdgcn_s_barrier();

        // ---- phase 2: reads {A-half1}; stages B-half1(kt+1); no wait
        LOADA(A, 1, a);
        stageB(db ^ 1, 1, k1);
        __builtin_amdgcn_s_barrier();
        __builtin_amdgcn_s_setprio(1);
        MMQ(1, 0, a, b0f);
        __builtin_amdgcn_s_setprio(0);
        __builtin_amdgcn_s_barrier();

        // ---- phase 3: no reads; stages A-half1(kt+1); vmcnt(4)
        stageA(db ^ 1, 1, k1);
        asm volatile("s_waitcnt vmcnt(4)" ::: "memory");
        __builtin_amdgcn_s_barrier();
        __builtin_amdgcn_s_setprio(1);
        MMQ(1, 1, a, b1f);
        __builtin_amdgcn_s_setprio(0);
        __builtin_amdgcn_s_barrier();
    }

    // ---- epilogue K-tile (NT-1): drain everything once, no staging
    asm volatile("s_waitcnt vmcnt(0)" ::: "memory");
    __builtin_amdgcn_s_barrier();
    {
        const signed char* A = sA[(NT - 1) & 1];
        const signed char* B = sB[(NT - 1) & 1];
        LOADA(A, 0, a);
        LOADB(B, 0, b0f);
        LOADB(B, 1, b1f);
        __builtin_amdgcn_s_setprio(1);
        MMQ(0, 0, a, b0f);
        MMQ(0, 1, a, b1f);
        __builtin_amdgcn_s_setprio(0);
        LOADA(A, 1, a);
        __builtin_amdgcn_s_setprio(1);
        MMQ(1, 0, a, b0f);
        MMQ(1, 1, a, b1f);
        __builtin_amdgcn_s_setprio(0);
    }

    // ---- output epilogue: D reg r of lane l -> row (l>>4)*4+r, col l&15 per frag
    const int mrow0 = m0 + wm * 128 + ((lane >> 4) << 2);
    const int ncol0 = n0 + wn * 64 + (lane & 15);
    float xsv[8][4];
#pragma unroll
    for (int mi = 0; mi < 8; ++mi)
#pragma unroll
        for (int r = 0; r < 4; ++r) xsv[mi][r] = xs[mrow0 + mi * 16 + r];

#pragma unroll
    for (int ni = 0; ni < 4; ++ni) {
        const int n = ncol0 + ni * 16;
        const float sc = scale[n];
        const float bs = bias[n];
#pragma unroll
        for (int mi = 0; mi < 8; ++mi) {
#pragma unroll
            for (int r = 0; r < 4; ++r) {
                const int m = mrow0 + mi * 16 + r;
                out[(size_t)m * N + n] = (float)acc[mi][ni][r] * xsv[mi][r] * sc + bs;
            }
        }
    }
}

extern "C" void kernel_launch(void* const* d_in, const int* in_sizes, int n_in,
                              void* d_out, int out_size, void* d_ws, size_t ws_size,
                              hipStream_t stream) {
    const float* x     = (const float*)d_in[0];
    const int*   w32   = (const int*)d_in[1];
    const float* scale = (const float*)d_in[2];
    const float* bias  = (const float*)d_in[3];
    float* out = (float*)d_out;

    const int M = in_sizes[0] / K_DIM;   // 8192
    const int N = in_sizes[2];           // 11008

    char* ws = (char*)d_ws;
    signed char* xq = (signed char*)ws;                                  // M*K
    float* xs = (float*)(ws + (size_t)M * K_DIM);                        // M floats
    signed char* w8 = (signed char*)(ws + (size_t)M * K_DIM + (size_t)M * sizeof(float));  // N*K

    quant_kernel<<<M, 256, 0, stream>>>(x, xq, xs);

    const int n16 = (N * K_DIM) / 16;
    repack_kernel<<<(n16 + 255) / 256, 256, 0, stream>>>(w32, (int4*)w8, n16);

    gemm_kernel<<<dim3(N / BN, M / BM), 512, 0, stream>>>(xq, w8, xs, scale, bias, out, N);
}

// Round 3
// 588.423 us; speedup vs baseline: 1.0878x; 1.0878x over previous
//
#include <hip/hip_runtime.h>

typedef int v4i __attribute__((ext_vector_type(4)));

static constexpr int K_DIM = 4096;
static constexpr int BM = 256, BN = 256, BK = 128;   // BK=128 i8; staged as 2x K=64 halves
static constexpr int NT = K_DIM / BK;                 // 32 K-tiles

// ---------------- per-token dynamic quantization ----------------
__global__ __launch_bounds__(256) void quant_kernel(const float* __restrict__ x,
                                                    signed char* __restrict__ xq,
                                                    float* __restrict__ xs) {
    const int token = blockIdx.x;
    const float4* row = (const float4*)(x + (size_t)token * K_DIM);
    const int t = threadIdx.x;
    float4 v[4];
    float m = 0.f;
#pragma unroll
    for (int i = 0; i < 4; ++i) {
        v[i] = row[t * 4 + i];
        m = fmaxf(m, fabsf(v[i].x));
        m = fmaxf(m, fabsf(v[i].y));
        m = fmaxf(m, fabsf(v[i].z));
        m = fmaxf(m, fabsf(v[i].w));
    }
#pragma unroll
    for (int d = 32; d > 0; d >>= 1) m = fmaxf(m, __shfl_xor(m, d));
    __shared__ float red[4];
    if ((t & 63) == 0) red[t >> 6] = m;
    __syncthreads();
    const float am = fmaxf(fmaxf(red[0], red[1]), fmaxf(red[2], red[3]));
    const float s = fmaxf(am, 1e-8f) * (1.0f / 127.0f);
    const float inv = 127.0f / fmaxf(am, 1e-8f);

    int pk[4];
#pragma unroll
    for (int i = 0; i < 4; ++i) {
        int q0 = (int)fminf(127.f, fmaxf(-127.f, rintf(v[i].x * inv)));
        int q1 = (int)fminf(127.f, fmaxf(-127.f, rintf(v[i].y * inv)));
        int q2 = (int)fminf(127.f, fmaxf(-127.f, rintf(v[i].z * inv)));
        int q3 = (int)fminf(127.f, fmaxf(-127.f, rintf(v[i].w * inv)));
        pk[i] = (q0 & 255) | ((q1 & 255) << 8) | ((q2 & 255) << 16) | (q3 << 24);
    }
    ((int4*)(xq + (size_t)token * K_DIM))[t] = make_int4(pk[0], pk[1], pk[2], pk[3]);
    if (t == 0) xs[token] = s;
}

// ---------------- weight repack: int32 -> packed int8 ----------------
__global__ __launch_bounds__(256) void repack_kernel(const int* __restrict__ w32,
                                                     int4* __restrict__ w8,
                                                     int n16) {
    const int idx = blockIdx.x * 256 + threadIdx.x;
    if (idx >= n16) return;
    const int4* src = (const int4*)w32 + (size_t)idx * 4;
    int4 a = src[0], b = src[1], c = src[2], d = src[3];
    int p0 = (a.x & 255) | ((a.y & 255) << 8) | ((a.z & 255) << 16) | (a.w << 24);
    int p1 = (b.x & 255) | ((b.y & 255) << 8) | ((b.z & 255) << 16) | (b.w << 24);
    int p2 = (c.x & 255) | ((c.y & 255) << 8) | ((c.z & 255) << 16) | (c.w << 24);
    int p3 = (d.x & 255) | ((d.y & 255) << 8) | ((d.z & 255) << 16) | (d.w << 24);
    w8[idx] = make_int4(p0, p1, p2, p3);
}

// ---- phase helpers (indices compile-time after unroll) ----
// LDS geometry: unit = [256 rows][64 B], flat: sX[buf*32768 + kh*16384 + row*64 + unit*16]
#define LOADA(KSBASE)                                                                 \
    _Pragma("unroll") for (int mi = 0; mi < 8; ++mi)                                  \
        a[mi] = *(const v4i*)&sAf[(KSBASE) + roffA + mi * 1024];
#define LOADB(KSBASE, NH, DST)                                                        \
    _Pragma("unroll") for (int ni = 0; ni < 2; ++ni)                                  \
        DST[ni] = *(const v4i*)&sBf[(KSBASE) + roffB + (NH) * 2048 + ni * 1024];
#define MMQ(NH, BF)                                                                   \
    _Pragma("unroll") for (int mi = 0; mi < 8; ++mi)                                  \
    _Pragma("unroll") for (int ni = 0; ni < 2; ++ni)                                  \
        acc[mi][(NH) * 2 + ni] = __builtin_amdgcn_mfma_i32_16x16x64_i8(               \
            a[mi], BF[ni], acc[mi][(NH) * 2 + ni], 0, 0, 0);

// ---------------- int8 MFMA GEMM, 256x256 tile, K-half-unit 8-phase schedule ----
__global__ __launch_bounds__(512, 2) void gemm_kernel(const signed char* __restrict__ xq,
                                                      const signed char* __restrict__ w8,
                                                      const float* __restrict__ xs,
                                                      const float* __restrict__ scale,
                                                      const float* __restrict__ bias,
                                                      float* __restrict__ out,
                                                      int N) {
    __shared__ __align__(16) signed char sAf[2 * 2 * 16384];   // [buf][khalf][256*64]
    __shared__ __align__(16) signed char sBf[2 * 2 * 16384];

    const int tid = threadIdx.x;
    const int lane = tid & 63;
    const int wid = tid >> 6;          // 8 waves: 2(M) x 4(N)
    const int wm = wid >> 2;
    const int wn = wid & 3;

    // T1: XCD-aware bijective swizzle (grid = 43 x 32 = 1376, divisible by 8)
    const int nwg = gridDim.x * gridDim.y;
    int flat = blockIdx.y * gridDim.x + blockIdx.x;
    if ((nwg & 7) == 0) flat = (flat & 7) * (nwg >> 3) + (flat >> 3);
    const int by = flat % gridDim.y;
    const int bx = flat / gridDim.y;
    const int m0 = by * BM;
    const int n0 = bx * BN;

    v4i acc[8][4];
    const v4i vzero = {0, 0, 0, 0};
#pragma unroll
    for (int i = 0; i < 8; ++i)
#pragma unroll
        for (int j = 0; j < 4; ++j) acc[i][j] = vzero;

    // ---- staging: write-side swizzle (per-thread constant source unit) ----
    // LDS row = j*128 + wid*16 + (lane>>2); unit_w = lane&3; src unit = unit_w ^ f(row)
    // f(row) = (row&3)^((row>>2)&3) = ((lane>>2)&3)^((lane>>4)&3)
    const int swz_w = (((tid & 3) ^ ((tid >> 2) & 3) ^ ((tid >> 4) & 3)) << 4);
    const signed char* srcA = xq + ((size_t)m0 + wid * 16 + ((tid & 63) >> 2)) * K_DIM + swz_w;
    const signed char* srcB = w8 + ((size_t)n0 + wid * 16 + ((tid & 63) >> 2)) * K_DIM + swz_w;

    auto stageA = [&](int buf, int kh, int kbyte) {
#pragma unroll
        for (int j = 0; j < 2; ++j) {
            __builtin_amdgcn_global_load_lds(
                (const __attribute__((address_space(1))) void*)(srcA + (size_t)j * 128 * K_DIM + kbyte + kh * 64),
                (__attribute__((address_space(3))) void*)&sAf[buf * 32768 + kh * 16384 + j * 8192 + wid * 1024],
                16, 0, 0);
        }
    };
    auto stageB = [&](int buf, int kh, int kbyte) {
#pragma unroll
        for (int j = 0; j < 2; ++j) {
            __builtin_amdgcn_global_load_lds(
                (const __attribute__((address_space(1))) void*)(srcB + (size_t)j * 128 * K_DIM + kbyte + kh * 64),
                (__attribute__((address_space(3))) void*)&sBf[buf * 32768 + kh * 16384 + j * 8192 + wid * 1024],
                16, 0, 0);
        }
    };

    // ---- read-side: per-lane constant swizzled unit ----
    // frag row = R0 + (lane&15); f(row) = (lane&3)^((lane>>2)&3); unit = lane>>4
    const int unitp = (((lane >> 4) ^ (lane & 3) ^ ((lane >> 2) & 3)) << 4);
    const int roffA = (wm * 128 + (lane & 15)) * 64 + unitp;
    const int roffB = (wn * 64 + (lane & 15)) * 64 + unitp;

    v4i a[8], b[2], b2[2];

    // prologue: stage all 4 units of K-tile 0 into buf 0
    stageA(0, 0, 0); stageB(0, 0, 0); stageA(0, 1, 0); stageB(0, 1, 0);
    asm volatile("s_waitcnt vmcnt(0)" ::: "memory");
    __builtin_amdgcn_s_barrier();

    for (int kt = 0; kt < NT - 1; ++kt) {
        const int db = kt & 1;
        const int kb = (kt + 1) * BK;
        const int A0 = db * 32768, A1 = A0 + 16384;
        const int B0 = db * 32768, B1 = B0 + 16384;

        // ---- phase 0: reads A(ks0) + B(nh0,ks0); stage A-k0(kt+1)
        LOADA(A0);
        LOADB(B0, 0, b);
        stageA(db ^ 1, 0, kb);
        __builtin_amdgcn_s_barrier();
        asm volatile("s_waitcnt lgkmcnt(0)" ::: "memory");
        __builtin_amdgcn_s_setprio(1);
        MMQ(0, b);
        __builtin_amdgcn_s_setprio(0);
        __builtin_amdgcn_s_barrier();

        // ---- phase 1: reads B(nh1,ks0); stage B-k0(kt+1); vmcnt(4) -> drains {A-k1,B-k1}(kt)
        LOADB(B0, 1, b2);
        stageB(db ^ 1, 0, kb);
        asm volatile("s_waitcnt vmcnt(4)" ::: "memory");
        __builtin_amdgcn_s_barrier();
        asm volatile("s_waitcnt lgkmcnt(0)" ::: "memory");
        __builtin_amdgcn_s_setprio(1);
        MMQ(1, b2);
        __builtin_amdgcn_s_setprio(0);
        __builtin_amdgcn_s_barrier();

        // ---- phase 2: reads A(ks1) + B(nh0,ks1); stage A-k1(kt+1)
        LOADA(A1);
        LOADB(B1, 0, b);
        stageA(db ^ 1, 1, kb);
        __builtin_amdgcn_s_barrier();
        asm volatile("s_waitcnt lgkmcnt(0)" ::: "memory");
        __builtin_amdgcn_s_setprio(1);
        MMQ(0, b);
        __builtin_amdgcn_s_setprio(0);
        __builtin_amdgcn_s_barrier();

        // ---- phase 3: reads B(nh1,ks1); stage B-k1(kt+1); vmcnt(4) -> drains {A-k0,B-k0}(kt+1)
        LOADB(B1, 1, b2);
        stageB(db ^ 1, 1, kb);
        asm volatile("s_waitcnt vmcnt(4)" ::: "memory");
        __builtin_amdgcn_s_barrier();
        asm volatile("s_waitcnt lgkmcnt(0)" ::: "memory");
        __builtin_amdgcn_s_setprio(1);
        MMQ(1, b2);
        __builtin_amdgcn_s_setprio(0);
        __builtin_amdgcn_s_barrier();
    }

    // ---- last K-tile: drain remaining {A-k1,B-k1}(NT-1), then 4 phases, no staging
    asm volatile("s_waitcnt vmcnt(0)" ::: "memory");
    __builtin_amdgcn_s_barrier();
    {
        const int db = (NT - 1) & 1;
        const int A0 = db * 32768, A1 = A0 + 16384;
        LOADA(A0);
        LOADB(A0, 0, b);
        LOADB(A0, 1, b2);
        asm volatile("s_waitcnt lgkmcnt(0)" ::: "memory");
        __builtin_amdgcn_s_setprio(1);
        MMQ(0, b);
        MMQ(1, b2);
        __builtin_amdgcn_s_setprio(0);
        LOADA(A1);
        LOADB(A1, 0, b);
        LOADB(A1, 1, b2);
        asm volatile("s_waitcnt lgkmcnt(0)" ::: "memory");
        __builtin_amdgcn_s_setprio(1);
        MMQ(0, b);
        MMQ(1, b2);
        __builtin_amdgcn_s_setprio(0);
    }

    // ---- output epilogue: D reg r of lane l -> row (l>>4)*4+r, col l&15 per frag
    const int mrow0 = m0 + wm * 128 + ((lane >> 4) << 2);
    const int ncol0 = n0 + wn * 64 + (lane & 15);
    float xsv[8][4];
#pragma unroll
    for (int mi = 0; mi < 8; ++mi)
#pragma unroll
        for (int r = 0; r < 4; ++r) xsv[mi][r] = xs[mrow0 + mi * 16 + r];

#pragma unroll
    for (int ni = 0; ni < 4; ++ni) {
        const int n = ncol0 + ni * 16;
        const float sc = scale[n];
        const float bs = bias[n];
#pragma unroll
        for (int mi = 0; mi < 8; ++mi) {
#pragma unroll
            for (int r = 0; r < 4; ++r) {
                const int m = mrow0 + mi * 16 + r;
                out[(size_t)m * N + n] = (float)acc[mi][ni][r] * xsv[mi][r] * sc + bs;
            }
        }
    }
}

extern "C" void kernel_launch(void* const* d_in, const int* in_sizes, int n_in,
                              void* d_out, int out_size, void* d_ws, size_t ws_size,
                              hipStream_t stream) {
    const float* x     = (const float*)d_in[0];
    const int*   w32   = (const int*)d_in[1];
    const float* scale = (const float*)d_in[2];
    const float* bias  = (const float*)d_in[3];
    float* out = (float*)d_out;

    const int M = in_sizes[0] / K_DIM;   // 8192
    const int N = in_sizes[2];           // 11008

    char* ws = (char*)d_ws;
    signed char* xq = (signed char*)ws;                                  // M*K
    float* xs = (float*)(ws + (size_t)M * K_DIM);                        // M floats
    signed char* w8 = (signed char*)(ws + (size_t)M * K_DIM + (size_t)M * sizeof(float));  // N*K

    quant_kernel<<<M, 256, 0, stream>>>(x, xq, xs);

    const int n16 = (N * K_DIM) / 16;
    repack_kernel<<<(n16 + 255) / 256, 256, 0, stream>>>(w32, (int4*)w8, n16);

    gemm_kernel<<<dim3(N / BN, M / BM), 512, 0, stream>>>(xq, w8, xs, scale, bias, out, N);
}